// Round 5
// baseline (1197.120 us; speedup 1.0000x reference)
//
#include <hip/hip_runtime.h>
#include <hip/hip_bf16.h>
#include <math.h>

#define HID   1024
#define IN_D  600
#define IN_DP 608      // 600 padded to multiple of 32
#define BATCH 2048
#define TSTEP 20
#define BT    (BATCH * TSTEP)   // 40960
#define G3    3072

typedef __attribute__((ext_vector_type(8))) short bf16x8;
typedef __attribute__((ext_vector_type(4))) float f32x4;

#define GLB(p) ((const __attribute__((address_space(1))) void*)(p))
#define LDS(p) ((__attribute__((address_space(3))) void*)(p))

__device__ __forceinline__ short f2bf(float f) {
    __hip_bfloat16 b = __float2bfloat16(f);
    return *(short*)&b;
}
__device__ __forceinline__ float bf2f(short s) {
    __hip_bfloat16 b = *(__hip_bfloat16*)&s;
    return __bfloat162float(b);
}

// ---------------------------------------------------------------------------
// Input projection: gx[(t*B + b), n] = bf16( x_bf[b*T+t, :] . Wih[n, :] + bias )
// 128x128 tile, m97 structure. 1D grid with XCD-lockstep swizzle:
// xcd = id&7 owns n-blocks {xcd*3..xcd*3+2} x all 320 m-panels, m-major,
// so all 8 XCDs stream the A panels in lockstep (L3 serves each line once).
// ---------------------------------------------------------------------------
__global__ __launch_bounds__(256) void gemm_input(const short* __restrict__ X,
                                                  const short* __restrict__ W,
                                                  const float* __restrict__ b_ih,
                                                  short* __restrict__ gx) {
    __shared__ short sA[128 * 32];
    __shared__ short sB[128 * 32];

    const int id    = blockIdx.x;
    const int xcd   = id & 7;
    const int local = id >> 3;          // 0..959
    const int nsub  = local % 3;
    const int mblk  = local / 3;        // 0..319
    const int m0 = mblk * 128;
    const int n0 = (xcd * 3 + nsub) * 128;

    const int tid  = threadIdx.x;
    const int wave = tid >> 6;
    const int lane = tid & 63;
    const int wm = (wave >> 1) * 64;
    const int wn = (wave & 1) * 64;

    const int srow = tid >> 2;
    const int scol = (tid & 3) * 8;
    const int fm = lane & 15;
    const int fq = lane >> 4;

    f32x4 acc[4][4] = {};

    for (int k0 = 0; k0 < IN_DP; k0 += 32) {
#pragma unroll
        for (int j = 0; j < 2; ++j) {
            const short* ga = X + (size_t)(m0 + j * 64 + srow) * IN_DP + k0 + scol;
            __builtin_amdgcn_global_load_lds(GLB(ga), LDS(sA + j * 2048 + wave * 512), 16, 0, 0);
            const short* gb = W + (size_t)(n0 + j * 64 + srow) * IN_DP + k0 + scol;
            __builtin_amdgcn_global_load_lds(GLB(gb), LDS(sB + j * 2048 + wave * 512), 16, 0, 0);
        }
        __syncthreads();

        bf16x8 af[4], bf[4];
#pragma unroll
        for (int mi = 0; mi < 4; ++mi)
            af[mi] = *(const bf16x8*)(sA + (wm + mi * 16 + fm) * 32 + fq * 8);
#pragma unroll
        for (int ni = 0; ni < 4; ++ni)
            bf[ni] = *(const bf16x8*)(sB + (wn + ni * 16 + fm) * 32 + fq * 8);
#pragma unroll
        for (int mi = 0; mi < 4; ++mi)
#pragma unroll
            for (int ni = 0; ni < 4; ++ni)
                acc[mi][ni] = __builtin_amdgcn_mfma_f32_16x16x32_bf16(af[mi], bf[ni], acc[mi][ni], 0, 0, 0);
        __syncthreads();
    }

    // D frag: row = fq*4 + r, col = fm. Write to [t][b][3H] layout.
#pragma unroll
    for (int ni = 0; ni < 4; ++ni) {
        int gn = n0 + wn + ni * 16 + fm;
        float bias = b_ih[gn];
#pragma unroll
        for (int mi = 0; mi < 4; ++mi) {
#pragma unroll
            for (int r = 0; r < 4; ++r) {
                int gm = m0 + wm + mi * 16 + fq * 4 + r;   // = b*T + t
                int b = gm / TSTEP;
                int t = gm - b * TSTEP;
                gx[((size_t)t * BATCH + b) * G3 + gn] = f2bf(acc[mi][ni][r] + bias);
            }
        }
    }
}

// ---------------------------------------------------------------------------
// Fused recurrent step v2: 64(batch) x 32(hidden) x 3 gates per block,
// BK=64, double-buffered LDS, 16 barriers. 4 waves each own 16 m-rows.
// Grid 1024 (1D), XCD swizzle: xcd owns j-blocks {xcd*4..+3} x all 32 m
// (W slice 0.8 MB + h 4.2 MB stay L2-resident per XCD).
// ---------------------------------------------------------------------------
__global__ __launch_bounds__(256) void gru_step(const short* __restrict__ hb_in,
                                                const short* __restrict__ Whh,
                                                const short* __restrict__ gx,
                                                const float* __restrict__ b_hh,
                                                float* __restrict__ hf,
                                                short* __restrict__ hb_out,
                                                float* __restrict__ out,
                                                int t, int last) {
    __shared__ short sA[2][64 * 64];        // 2 x 8 KB
    __shared__ short sB[2][3 * 32 * 64];    // 2 x 12 KB

    const int id    = blockIdx.x;
    const int xcd   = id & 7;
    const int local = id >> 3;              // 0..127
    const int j0 = (xcd * 4 + (local & 3)) * 32;
    const int m0 = (local >> 2) * 64;

    const int tid  = threadIdx.x;
    const int wave = tid >> 6;
    const int lane = tid & 63;
    const int fm = lane & 15;
    const int fq = lane >> 4;

    const int srow = tid >> 3;          // 0..31
    const int scol = (tid & 7) * 8;

    f32x4 acc[3][2] = {};   // [gate][n-frag]

    // stage k-chunk kc (64 wide) into buffer bsel
    auto stage = [&](int kc, int bsel) {
        int k0 = kc * 64;
#pragma unroll
        for (int j = 0; j < 2; ++j) {
            const short* g = hb_in + (size_t)(m0 + j * 32 + srow) * HID + k0 + scol;
            __builtin_amdgcn_global_load_lds(GLB(g), LDS(&sA[bsel][(j * 32 + wave * 8) * 64]), 16, 0, 0);
        }
#pragma unroll
        for (int j = 0; j < 3; ++j) {
            const short* g = Whh + (size_t)(j * HID + j0 + srow) * HID + k0 + scol;
            __builtin_amdgcn_global_load_lds(GLB(g), LDS(&sB[bsel][(j * 32 + wave * 8) * 64]), 16, 0, 0);
        }
    };

    stage(0, 0);
    for (int ic = 0; ic < 16; ++ic) {
        int cur = ic & 1;
        __syncthreads();                     // drains staging for buf cur
        if (ic + 1 < 16) stage(ic + 1, cur ^ 1);

        bf16x8 af[2], bg[3][2][2];
#pragma unroll
        for (int kq = 0; kq < 2; ++kq)
            af[kq] = *(const bf16x8*)(&sA[cur][(wave * 16 + fm) * 64 + kq * 32 + fq * 8]);
#pragma unroll
        for (int g = 0; g < 3; ++g)
#pragma unroll
            for (int n = 0; n < 2; ++n)
#pragma unroll
                for (int kq = 0; kq < 2; ++kq)
                    bg[g][n][kq] = *(const bf16x8*)(&sB[cur][(g * 32 + n * 16 + fm) * 64 + kq * 32 + fq * 8]);
#pragma unroll
        for (int g = 0; g < 3; ++g)
#pragma unroll
            for (int n = 0; n < 2; ++n)
#pragma unroll
                for (int kq = 0; kq < 2; ++kq)
                    acc[g][n] = __builtin_amdgcn_mfma_f32_16x16x32_bf16(af[kq], bg[g][n][kq], acc[g][n], 0, 0, 0);
    }

    // Epilogue. D frag: row = fq*4 + r, col = fm.
    const short* gxt = gx + (size_t)t * BATCH * G3;
#pragma unroll
    for (int n = 0; n < 2; ++n) {
        int gj = j0 + n * 16 + fm;
        float bh_r = b_hh[gj];
        float bh_i = b_hh[HID + gj];
        float bh_n = b_hh[2 * HID + gj];
#pragma unroll
        for (int r = 0; r < 4; ++r) {
            int gm = m0 + wave * 16 + fq * 4 + r;   // batch row
            const short* gr = gxt + (size_t)gm * G3;
            float xr = bf2f(gr[gj]);
            float xi = bf2f(gr[HID + gj]);
            float xn = bf2f(gr[2 * HID + gj]);

            float rg = 1.0f / (1.0f + __expf(-(xr + acc[0][n][r] + bh_r)));
            float ig = 1.0f / (1.0f + __expf(-(xi + acc[1][n][r] + bh_i)));
            float ng = tanhf(xn + rg * (acc[2][n][r] + bh_n));

            size_t idx = (size_t)gm * HID + gj;
            float h  = hf[idx];
            float hy = ng + ig * (h - ng);
            hf[idx] = hy;
            hb_out[idx] = f2bf(hy);
            if (last) out[idx] = hy;
        }
    }
}

// x [BT,600] fp32 -> [BT,608] bf16 zero-padded
__global__ __launch_bounds__(256) void cvt_x(const float* __restrict__ X, short* __restrict__ Xb) {
    int r = blockIdx.x;
    for (int c = threadIdx.x; c < IN_DP; c += 256) {
        float v = (c < IN_D) ? X[(size_t)r * IN_D + c] : 0.f;
        Xb[(size_t)r * IN_DP + c] = f2bf(v);
    }
}

// W_ih [3072,600] fp32 -> [3072,608] bf16 zero-padded
__global__ __launch_bounds__(256) void cvt_wih(const float* __restrict__ W, short* __restrict__ Wb) {
    int r = blockIdx.x;
    for (int c = threadIdx.x; c < IN_DP; c += 256) {
        float v = (c < IN_D) ? W[(size_t)r * IN_D + c] : 0.f;
        Wb[(size_t)r * IN_DP + c] = f2bf(v);
    }
}

__global__ __launch_bounds__(256) void cvt_flat(const float* __restrict__ W, short* __restrict__ Wb, int n) {
    int i = blockIdx.x * 256 + threadIdx.x;
    if (i < n) Wb[i] = f2bf(W[i]);
}

extern "C" void kernel_launch(void* const* d_in, const int* in_sizes, int n_in,
                              void* d_out, int out_size, void* d_ws, size_t ws_size,
                              hipStream_t stream) {
    const float* x    = (const float*)d_in[0];  // [B, T, IN_D] = [BT, 600]
    const float* W_ih = (const float*)d_in[1];  // [3H, IN_D]
    const float* b_ih = (const float*)d_in[2];
    const float* W_hh = (const float*)d_in[3];  // [3H, HID]
    const float* b_hh = (const float*)d_in[4];
    float* out = (float*)d_out;                 // [B, HID]

    char* p = (char*)d_ws;
    short* gx     = (short*)p;  p += (size_t)BT * G3 * 2;       // 251.7 MB, [T][B][3H]
    short* x_bf   = (short*)p;  p += (size_t)BT * IN_DP * 2;    //  49.8 MB
    float* hf     = (float*)p;  p += (size_t)BATCH * HID * 4;   //   8.4 MB
    short* hb0    = (short*)p;  p += (size_t)BATCH * HID * 2;   //   4.2 MB
    short* hb1    = (short*)p;  p += (size_t)BATCH * HID * 2;   //   4.2 MB
    short* Wih_bf = (short*)p;  p += (size_t)G3 * IN_DP * 2;    //   3.7 MB
    short* Whh_bf = (short*)p;  p += (size_t)G3 * HID * 2;      //   6.3 MB
    // total ~328 MB

    cvt_wih<<<G3, 256, 0, stream>>>(W_ih, Wih_bf);
    cvt_flat<<<(G3 * HID + 255) / 256, 256, 0, stream>>>(W_hh, Whh_bf, G3 * HID);
    cvt_x<<<BT, 256, 0, stream>>>(x, x_bf);
    hipMemsetAsync(hf, 0, (size_t)BATCH * HID * 4, stream);
    hipMemsetAsync(hb0, 0, (size_t)BATCH * HID * 2, stream);

    // One big input projection over all timesteps: M = 40960, 1D swizzled grid
    gemm_input<<<7680, 256, 0, stream>>>(x_bf, Wih_bf, b_ih, gx);

    // 20 fused recurrent steps, 1D swizzled grid (1024 blocks)
    for (int t = 0; t < TSTEP; ++t) {
        const short* hin = (t & 1) ? hb1 : hb0;
        short* hout      = (t & 1) ? hb0 : hb1;
        gru_step<<<1024, 256, 0, stream>>>(hin, Whh_bf, gx, b_hh,
                                           hf, hout, out, t, t == TSTEP - 1 ? 1 : 0);
    }
}